// Round 3
// baseline (1261.912 us; speedup 1.0000x reference)
//
#include <hip/hip_runtime.h>
#include <math.h>

// Problem dims (fixed by reference): T=512 -> rows=511, V=32000, E=H=512.
#define ROWS 511
#define VV   32000
#define HH   512

// Scan constants
#define SLOTF   3584    // fast-path W-block size cap in floats
#define DARRCAP 26112   // LDS delta-history capacity (104448 B)
#define TBL     520     // table size (covers t+5 <= 513)
#define MAXQ    17      // float4 pairs per row in register bank (covers cip <= 68)

// Pad to multiple of 4 that is NOT a multiple of 8 (W row stride in floats).
__device__ __forceinline__ int pad4not8(int x) {
    int p = (x + 3) & ~3;
    if ((p & 7) == 0) p += 4;
    return p;
}
__device__ __forceinline__ int pad4(int x) { return (x + 3) & ~3; }

__device__ __forceinline__ int rfl(int x) { return __builtin_amdgcn_readfirstlane(x); }

// ---------------- fp32 tiled GEMM:  C[m,n] (+)= sum_k A[m,k]*B[n,k] ----------------
__global__ __launch_bounds__(256) void gemm_nt(
    const float* __restrict__ A, const float* __restrict__ B, float* __restrict__ C,
    int M, int lda, int ldb, int ldc, int kChunk, int useAtomic)
{
    __shared__ float As[16][68];   // k-major, padded
    __shared__ float Bs[16][68];
    const int tid = threadIdx.x;
    const int bn = blockIdx.x, bm = blockIdx.y, bz = blockIdx.z;
    const int row = tid >> 2;            // 0..63
    const int seg = (tid & 3) << 2;      // k sub-offset {0,4,8,12}
    const int tm  = (tid >> 4) << 2;     // 0,4,..,60
    const int tn  = (tid & 15) << 2;
    const int am = bm*64 + row;
    const size_t k0 = (size_t)bz * kChunk;
    const float* Ap = A + (size_t)am*lda + k0 + seg;
    const float* Bp = B + (size_t)(bn*64 + row)*ldb + k0 + seg;
    const bool aok = (am < M);
    float acc[4][4];
#pragma unroll
    for (int i=0;i<4;i++)
#pragma unroll
        for (int j=0;j<4;j++) acc[i][j]=0.f;

    for (int kt = 0; kt < kChunk; kt += 16) {
        float4 av = aok ? *(const float4*)(Ap + kt) : make_float4(0.f,0.f,0.f,0.f);
        float4 bv = *(const float4*)(Bp + kt);       // N is always a multiple of 64
        __syncthreads();
        As[seg+0][row]=av.x; As[seg+1][row]=av.y; As[seg+2][row]=av.z; As[seg+3][row]=av.w;
        Bs[seg+0][row]=bv.x; Bs[seg+1][row]=bv.y; Bs[seg+2][row]=bv.z; Bs[seg+3][row]=bv.w;
        __syncthreads();
#pragma unroll
        for (int k=0;k<16;k++){
            const float4 a  = *(const float4*)&As[k][tm];
            const float4 b4 = *(const float4*)&Bs[k][tn];
            float ar[4]={a.x,a.y,a.z,a.w};
            float br[4]={b4.x,b4.y,b4.z,b4.w};
#pragma unroll
            for (int i=0;i<4;i++)
#pragma unroll
                for (int j=0;j<4;j++)
                    acc[i][j] += ar[i]*br[j];
        }
    }
#pragma unroll
    for (int i=0;i<4;i++){
        int gm = bm*64 + tm + i;
        if (gm < M) {
            float* Cp = C + (size_t)gm*ldc + bn*64 + tn;
            if (useAtomic) {
                atomicAdd(Cp+0, acc[i][0]); atomicAdd(Cp+1, acc[i][1]);
                atomicAdd(Cp+2, acc[i][2]); atomicAdd(Cp+3, acc[i][3]);
            } else {
                *(float4*)Cp = make_float4(acc[i][0],acc[i][1],acc[i][2],acc[i][3]);
            }
        }
    }
}

// ---------------- R[j] = sum_i |W_h[j,i]| ----------------
__global__ __launch_bounds__(64) void rsum_kernel(const float* __restrict__ W_h, float* __restrict__ R)
{
    const int j = blockIdx.x;
    const int lane = threadIdx.x;
    float s = 0.f;
    for (int i = lane; i < HH; i += 64) s += fabsf(W_h[(size_t)j*HH + i]);
#pragma unroll
    for (int off = 32; off >= 1; off >>= 1) s += __shfl_down(s, off);
    if (lane == 0) R[j] = s;
}

// ---------------- classify: xp += b; S = step(xp); uncertain index lists ----------------
__global__ __launch_bounds__(512) void classify_kernel(
    float* __restrict__ xp, const float* __restrict__ b, const float* __restrict__ R,
    float* __restrict__ Hm, int* __restrict__ idxJ, int* __restrict__ cnt)
{
    const int t = blockIdx.x;       // 0..510
    const int j = threadIdx.x;      // 0..511
    __shared__ int c;
    if (j == 0) c = 0;
    __syncthreads();
    float v = xp[(size_t)t*HH + j] + b[j];
    xp[(size_t)t*HH + j] = v;
    Hm[(size_t)t*HH + j] = (v > 0.f) ? 1.f : 0.f;
    if (fabsf(v) < R[j] + 30.0f) {       // recurrent term bound: |W_h@h| <= R[j]
        int slot = atomicAdd(&c, 1);
        if (slot < 128) idxJ[t*128 + slot] = j;
    }
    __syncthreads();
    if (j == 0) cnt[t] = (c < 128) ? c : 128;
}

// ---------------- parallel prefixes: wsub block offsets + delta-history offsets ----------------
__global__ __launch_bounds__(512) void prefix_kernel(
    const int* __restrict__ cnt, int* __restrict__ offs, int* __restrict__ d4offs)
{
    __shared__ int sA[512];
    __shared__ int sB[512];
    const int t = threadIdx.x;
    int a = 0, b = 0;
    if (t >= 1 && t <= 510) a = cnt[t] * pad4not8(cnt[t-1]);   // cj * ci_pad
    if (t <= 510) b = pad4(cnt[t]);
    sA[t] = a; sB[t] = b;
    int va = a, vb = b;
    __syncthreads();
    for (int d = 1; d < 512; d <<= 1) {
        int ua = (t >= d) ? sA[t-d] : 0;
        int ub = (t >= d) ? sB[t-d] : 0;
        __syncthreads();
        va += ua; vb += ub;
        sA[t] = va; sB[t] = vb;
        __syncthreads();
    }
    if (t <= 510) offs[t] = va - a;     // exclusive prefix (multiple of 4)
    d4offs[t] = vb - b;                 // t=511 slot -> padded total
}

// ---------------- gather: pack W_h submatrix j-major + {zbase, step} pairs ----------------
__global__ __launch_bounds__(256) void gather_kernel(
    const float* __restrict__ W_h, const float* __restrict__ xp, const float* __restrict__ U,
    const int* __restrict__ idxJ, const int* __restrict__ cnt, const int* __restrict__ offs,
    float* __restrict__ wsub, int wsub_cap, float2* __restrict__ zs)
{
    const int t = blockIdx.x;       // 0..510
    const int cj = cnt[t];
    for (int jj = threadIdx.x; jj < cj; jj += 256) {
        int j = idxJ[t*128 + jj];
        float xpv = xp[(size_t)t*HH + j];
        float v = xpv;
        if (t > 0) v += U[(size_t)(t-1)*HH + j];
        zs[t*128 + jj] = make_float2(v, (xpv > 0.f) ? 1.f : 0.f);
    }
    if (t == 0) return;
    const int ci  = cnt[t-1];
    const int cip = pad4not8(ci);
    const int nw  = cj * cip;
    const int base = offs[t];
    if (base + nw > wsub_cap) return;    // scan falls back to direct W_h gather
    for (int r = 0; r < cj; ++r) {
        const float* Wrow = W_h + (size_t)idxJ[t*128 + r] * HH;
        for (int c = threadIdx.x; c < cip; c += 256)
            wsub[base + r*cip + c] = (c < ci) ? Wrow[idxJ[(t-1)*128 + c]] : 0.f;
    }
}

// ---------------- sequential scan: SINGLE WAVE, depth-2 register pipeline ----------------
// Round change (398 us -> target ~140 us):
//  * __launch_bounds__(64, 1): this kernel is ONE wave on the whole GPU; occupancy
//    is meaningless. Round-2's VGPR_Count=152 shows the allocator (targeting default
//    occupancy) shortened live ranges by sinking the prefetch loads toward their
//    uses, collapsing the software pipeline to depth ~0 (full HBM latency exposed
//    every step). minWavesPerEU=1 unlocks the ~512-VGPR budget so the W banks stay
//    resident and the loads stay hoisted.
//  * depth-2 prefetch with THREE statically-named banks W0/W1/W2 (204 VGPRs): the
//    wait before compute(t) covers loads issued two bodies earlier -> latency
//    condition 3P >= L+C instead of P >= L+C. Loop unrolled x3 (510 = 3*170), all
//    bank indices compile-time constants. Exactly 18 unconditional clamped VMEM
//    loads per body -> compiler emits counted vmcnt(36) before each bank use.
__global__ __launch_bounds__(64, 1) void scan_kernel(
    const float2* __restrict__ zs, const int* __restrict__ idxJ,
    const int* __restrict__ cnt, const int* __restrict__ offs, const int* __restrict__ d4offs,
    const float* __restrict__ wsub, int wsub_cap,
    const float* __restrict__ W_h, float* __restrict__ Hm, float* __restrict__ darrg)
{
    __shared__ __align__(16) float  darr[DARRCAP];        // 104448 B
    __shared__ __align__(16) float  db[2][132];           // overflow-mode ping-pong
    __shared__ __align__(16) int4   rec[TBL];             //   8320 B {cnt, offs, d4offs, 0}
    const int lane = threadIdx.x;
    const float* zsf = (const float*)zs;

    for (int i = lane; i < TBL; i += 64) {
        int c = (i < ROWS) ? cnt[i]    : 0;
        int o = (i < ROWS) ? offs[i]   : 0;
        int d = (i < ROWS) ? d4offs[i] : d4offs[511];
        rec[i] = make_int4(c, o, d, 0);
    }
    for (int i = lane * 4; i < DARRCAP; i += 256)
        *(float4*)&darr[i] = make_float4(0.f, 0.f, 0.f, 0.f);
    for (int i = lane; i < 132; i += 64) { db[0][i] = 0.f; db[1][i] = 0.f; }
    __syncthreads();

    const int  total   = rfl(rec[511].z);
    const bool useDarr = (total <= DARRCAP - 64);

    // ---- t = 0: h = sigmoid(zbase), delta = h - step ----
    {
        const int cj0 = rfl(rec[0].x);
        for (int jj = lane; jj < cj0; jj += 64) {
            float2 zz = zs[jj];
            float h = 1.f / (1.f + __expf(-zz.x));
            float d = h - zz.y;
            if (useDarr) darr[jj] = d;
            else { db[0][jj] = d; Hm[idxJ[jj]] = h; }
        }
    }

    // ---- three register W banks + prefetched z ----
    float4 W0[MAXQ], W1[MAXQ], W2[MAXQ];
    float2 z0, z1, z2;

    // carried wave-uniform bookkeeping
    int ciP, sd4P;               // step t-1: cnt, d-offset
    int cjC, sd4C, n4C; bool fastC;   // step t (current compute)
    int cjN, sd4N, n4N; bool fastN;   // step t+1
    int cj2, wb2, sd42;          // step t+2 raw rec (prefetched this body)

    // Issue prefetch of W(step TT) into BANK and z(step TT) into ZB.
    // CJPREV = cnt[TT-1] (row length), CJT/WBT = cnt/offs of TT.
#define PF(CJPREV, CJT, WBT, BANK, ZB, TT, N4OUT, FASTOUT) do {                 \
        int cip_ = pad4not8(CJPREV);                                            \
        N4OUT = cip_ >> 2;                                                      \
        FASTOUT = ((CJT) <= 64) && (cip_ <= 68) &&                              \
                  ((long)(CJT) * cip_ <= SLOTF) && ((WBT) + SLOTF <= wsub_cap); \
        int row_ = min(lane, max((CJT) - 1, 0));                                \
        const float* gW_ = wsub + (FASTOUT ? ((WBT) + row_ * cip_) : 0);        \
        _Pragma("unroll")                                                       \
        for (int q = 0; q < MAXQ; ++q) {                                        \
            int off_ = (q < N4OUT) ? (q << 2) : 0;                              \
            BANK[q] = *(const float4*)(gW_ + off_);                             \
        }                                                                       \
        ZB = *(const float2*)&zsf[(size_t)(TT) * 256 + (lane << 1)];            \
    } while (0)

#define COMPUTE(TT, CURW, ZC) do {                                              \
        const float* dvec_ = useDarr ? &darr[sd4P] : db[((TT) - 1) & 1];        \
        if (fastC) {                                                            \
            if (lane < cjC) {                                                   \
                const float4* dr_ = (const float4*)dvec_;                       \
                float4 Dv[MAXQ];                                                \
                _Pragma("unroll")                                               \
                for (int g = 0; g < MAXQ; g += 4) {                             \
                    if (g < n4C) {                                              \
                        _Pragma("unroll")                                       \
                        for (int q = g; q < g + 4 && q < MAXQ; ++q)             \
                            Dv[q] = dr_[q];                                     \
                    }                                                           \
                }                                                               \
                float a0 = 0.f, a1 = 0.f, a2 = 0.f, a3 = 0.f;                   \
                _Pragma("unroll")                                               \
                for (int q = 0; q < MAXQ; ++q) {                                \
                    if (q < n4C) {                                              \
                        a0 += CURW[q].x * Dv[q].x; a1 += CURW[q].y * Dv[q].y;   \
                        a2 += CURW[q].z * Dv[q].z; a3 += CURW[q].w * Dv[q].w;   \
                    }                                                           \
                }                                                               \
                float z = ZC.x + (a0 + a1) + (a2 + a3);                         \
                float h = 1.f / (1.f + __expf(-z));                             \
                float d = h - ZC.y;                                             \
                if (useDarr) darr[sd4C + lane] = d;                             \
                else { db[(TT) & 1][lane] = d;                                  \
                       Hm[(size_t)(TT)*HH + idxJ[(TT)*128 + lane]] = h; }       \
            }                                                                   \
        } else {                                                                \
            for (int jj = lane; jj < cjC; jj += 64) {                           \
                int j = idxJ[(TT)*128 + jj];                                    \
                float2 zz = zs[(size_t)(TT)*128 + jj];                          \
                float zv = zz.x;                                                \
                for (int ii = 0; ii < ciP; ++ii)                                \
                    zv += W_h[(size_t)j*HH + idxJ[((TT)-1)*128 + ii]] * dvec_[ii]; \
                float h = 1.f / (1.f + __expf(-zv));                            \
                float dd = h - zz.y;                                            \
                if (useDarr) darr[sd4C + jj] = dd;                              \
                else { db[(TT) & 1][jj] = dd;                                   \
                       Hm[(size_t)(TT)*HH + j] = h; }                           \
            }                                                                   \
        }                                                                       \
    } while (0)

    // body for step TT: prefetch TT+2 into PFB, compute TT from CWB
#define BODY(TT, PFB, ZPFB, CWB, ZCW) do {                                      \
        int n4p_; bool fp_;                                                     \
        PF(cjN, cj2, wb2, PFB, ZPFB, (TT) + 2, n4p_, fp_);                      \
        int4 rn3_ = rec[(TT) + 3];                                              \
        COMPUTE((TT), CWB, ZCW);                                                \
        ciP = cjC; sd4P = sd4C;                                                 \
        cjC = cjN; sd4C = sd4N; n4C = n4N; fastC = fastN;                       \
        cjN = cj2; sd4N = sd42; n4N = n4p_; fastN = fp_;                        \
        cj2 = rfl(rn3_.x); wb2 = rfl(rn3_.y); sd42 = rfl(rn3_.z);               \
    } while (0)

    // ---- prime: prefetch steps 1 (->W1) and 2 (->W2) ----
    ciP  = rfl(rec[0].x);
    sd4P = rfl(rec[0].z);
    {
        int cj1 = rfl(rec[1].x), wb1 = rfl(rec[1].y);
        cjC = cj1; sd4C = rfl(rec[1].z);
        PF(ciP, cj1, wb1, W1, z1, 1, n4C, fastC);
        int cjB = rfl(rec[2].x), wbB = rfl(rec[2].y);
        cjN = cjB; sd4N = rfl(rec[2].z);
        PF(cjC, cjB, wbB, W2, z2, 2, n4N, fastN);
        cj2 = rfl(rec[3].x); wb2 = rfl(rec[3].y); sd42 = rfl(rec[3].z);
    }

    for (int t = 1; t <= 510; t += 3) {      // 510 = 3 * 170, exact
        BODY(t,     W0, z0, W1, z1);         // compute t   from W1, prefetch t+2 -> W0
        BODY(t + 1, W1, z1, W2, z2);         // compute t+1 from W2, prefetch t+3 -> W1
        BODY(t + 2, W2, z2, W0, z0);         // compute t+2 from W0, prefetch t+4 -> W2
    }

    // dump delta history for the parallel scatter kernel
    if (useDarr) {
        for (int i = lane * 4; i < total; i += 256)
            *(float4*)&darrg[i] = *(float4*)&darr[i];
    }
#undef PF
#undef COMPUTE
#undef BODY
}

// ---------------- parallel scatter: Hm[t, idxJ] = step + delta ----------------
__global__ __launch_bounds__(64) void scatter_kernel(
    const float2* __restrict__ zs, const int* __restrict__ idxJ,
    const int* __restrict__ cnt, const int* __restrict__ d4offs,
    const float* __restrict__ darrg, float* __restrict__ Hm)
{
    if (d4offs[511] > DARRCAP - 64) return;   // overflow mode: scan wrote Hm directly
    const int t = blockIdx.x;
    const int c = cnt[t];
    for (int jj = threadIdx.x; jj < c; jj += 64)
        Hm[(size_t)t*HH + idxJ[t*128 + jj]] = zs[(size_t)t*128 + jj].y + darrg[d4offs[t] + jj];
}

// ---------------- row softmax over V=32000, in place on d_out ----------------
__global__ __launch_bounds__(256) void softmax_kernel(float* __restrict__ out)
{
    const int row = blockIdx.x;
    const int tid = threadIdx.x;
    float* p = out + (size_t)row * VV;
    float m = -INFINITY, l = 0.f;
    for (int i = tid; i < VV; i += 256) {          // 125 iters exactly
        float x = p[i];
        if (x > m) { l = l * __expf(m - x) + 1.f; m = x; }
        else       { l += __expf(x - m); }
    }
#pragma unroll
    for (int off = 32; off >= 1; off >>= 1) {
        float m2 = __shfl_down(m, off);
        float l2 = __shfl_down(l, off);
        float M  = fmaxf(m, m2);
        l = l * __expf(m - M) + l2 * __expf(m2 - M);
        m = M;
    }
    __shared__ float sm[4], sl[4];
    const int wid = tid >> 6, lane = tid & 63;
    if (lane == 0) { sm[wid] = m; sl[wid] = l; }
    __syncthreads();
    if (tid == 0) {
        float M = sm[0], L = sl[0];
        for (int w = 1; w < 4; ++w) {
            float M2 = fmaxf(M, sm[w]);
            L = L * __expf(M - M2) + sl[w] * __expf(sm[w] - M2);
            M = M2;
        }
        sm[0] = M; sl[0] = 1.0f / L;
    }
    __syncthreads();
    const float M = sm[0], inv = sl[0];
    for (int i = tid; i < VV; i += 256) p[i] = __expf(p[i] - M) * inv;
}

// ---------------- launcher ----------------
extern "C" void kernel_launch(void* const* d_in, const int* in_sizes, int n_in,
                              void* d_out, int out_size, void* d_ws, size_t ws_size,
                              hipStream_t stream)
{
    const float* sent = (const float*)d_in[0];
    const float* W_e  = (const float*)d_in[1];
    const float* W_x  = (const float*)d_in[2];
    const float* W_h  = (const float*)d_in[3];
    const float* W_p  = (const float*)d_in[4];
    const float* b    = (const float*)d_in[5];
    float* out = (float*)d_out;
    float* ws  = (float*)d_ws;

    // workspace layout (float offsets)
    float*  emb    = ws;                      // 262144
    float*  xp     = ws + 262144;             // 262144
    float*  U      = ws + 524288;             // 262144
    float*  Hm     = ws + 786432;             // 262144
    float*  R      = ws + 1048576;            // 512
    int*    cnt    = (int*)(ws + 1049088);    // 512
    int*    idxJ   = (int*)(ws + 1049600);    // 511*128 -> 65536
    int*    offs   = (int*)(ws + 1115136);    // 512
    int*    d4offs = (int*)(ws + 1115648);    // 512
    float2* zs     = (float2*)(ws + 1116160); // 511*128 float2 -> 130816 floats
    float*  darrg  = ws + 1246976;            // 26112
    float*  wsub   = ws + 1273088;
    long avail = (long)(ws_size / 4) - 1273088;
    int wsub_cap = (avail > 8388608L) ? 8388608 : (avail > 0 ? (int)avail : 0);

    // zero the atomic-accumulated buffers (emb, xp, U)
    hipMemsetAsync(ws, 0, (size_t)786432 * sizeof(float), stream);

    rsum_kernel<<<512, 64, 0, stream>>>(W_h, R);

    // emb = sent[:511] @ W_e^T   (K=32000, split-K 8)
    gemm_nt<<<dim3(8, 8, 8), 256, 0, stream>>>(sent, W_e, emb, ROWS, VV, VV, HH, 4000, 1);
    // xp_raw = emb @ W_x^T       (K=512, split-K 4)
    gemm_nt<<<dim3(8, 8, 4), 256, 0, stream>>>(emb, W_x, xp, ROWS, HH, HH, HH, 128, 1);

    classify_kernel<<<ROWS, 512, 0, stream>>>(xp, b, R, Hm, idxJ, cnt);

    // U = S @ W_h^T  (S currently stored in Hm)
    gemm_nt<<<dim3(8, 8, 4), 256, 0, stream>>>(Hm, W_h, U, ROWS, HH, HH, HH, 128, 1);

    prefix_kernel<<<1, 512, 0, stream>>>(cnt, offs, d4offs);
    gather_kernel<<<ROWS, 256, 0, stream>>>(W_h, xp, U, idxJ, cnt, offs, wsub, wsub_cap, zs);
    scan_kernel<<<1, 64, 0, stream>>>(zs, idxJ, cnt, offs, d4offs, wsub, wsub_cap, W_h, Hm, darrg);
    scatter_kernel<<<ROWS, 64, 0, stream>>>(zs, idxJ, cnt, d4offs, darrg, Hm);

    // logits = H @ W_p^T  -> d_out
    gemm_nt<<<dim3(500, 8, 1), 256, 0, stream>>>(Hm, W_p, out, ROWS, HH, HH, VV, 512, 0);
    softmax_kernel<<<ROWS, 256, 0, stream>>>(out);
}